// Round 13
// baseline (417.341 us; speedup 1.0000x reference)
//
#include <hip/hip_runtime.h>
#include <hip/hip_fp16.h>

#define BATCH 4096
#define NCLS  4
#define INDIM 100
#define INITD 64
#define DD    164     // IN_DIM + INIT_DIM
#define DDP   192     // K padded to 6*32 for MFMA
#define MM    33      // PCAP + 1
#define TT    16
#define NOUT  16      // OUT_CAPS

typedef _Float16 f16;
typedef f16 f16x8 __attribute__((ext_vector_type(8)));
typedef f16 f16x2 __attribute__((ext_vector_type(2)));
typedef float f32x4 __attribute__((ext_vector_type(4)));

__device__ __forceinline__ f16x2 u2h2(unsigned u){
  union { unsigned u; f16x2 h; } c; c.u = u; return c.h;
}

// ======================= k_pre: entmax (bisection) + leaf norm =======================
// entmax15(x): x' = (x - max)/2; solve sum(clip(x'-tau,0)^2) = 1 by bisection.
// blocks 0..527: blk = m*16+n; 16 entmax problems (one per t), one per 16-lane group.
// block 528: m1 masks (3 waves) + leaves (wave 3). block 529: m2 masks (3 waves).
__global__ __launch_bounds__(256) void k_pre(const float* __restrict__ route_w,
    const float* __restrict__ m1_w, const float* __restrict__ m2_w,
    const float* __restrict__ leaves,
    __half* __restrict__ w2t, float* __restrict__ mask1, float* __restrict__ mask2,
    float* __restrict__ lh_t){
  int blk = blockIdx.x, tid = threadIdx.x;
  if (blk < 528){
    const float* base = route_w + (size_t)blk*DD*16;   // [164][16] slab for (m,n)
    int l  = tid & 63;
    int t  = (tid>>6)*4 + (l&3);
    int lg = l>>2;                                     // d = lg + 16*i
    float v[11];
    float mx = -1e30f;
    #pragma unroll
    for (int i=0;i<11;++i){
      int d = lg + 16*i;
      v[i] = (d < DD) ? base[d*16 + t] : -1e30f;
      mx = fmaxf(mx, v[i]);
    }
    #pragma unroll
    for (int msk=4; msk<=32; msk<<=1) mx = fmaxf(mx, __shfl_xor(mx, msk));
    #pragma unroll
    for (int i=0;i<11;++i) v[i] = (v[i]-mx)*0.5f;
    float lo=-1.0f, hi=0.0f;
    for (int it=0; it<30; ++it){
      float mid = 0.5f*(lo+hi), g=0.0f;
      #pragma unroll
      for (int i=0;i<11;++i){ float tv = fmaxf(v[i]-mid, 0.0f); g += tv*tv; }
      #pragma unroll
      for (int msk=4; msk<=32; msk<<=1) g += __shfl_xor(g, msk);
      if (g > 1.0f) lo = mid; else hi = mid;           // uniform branch
    }
    float tau = 0.5f*(lo+hi);
    __half* wout = w2t + (size_t)(blk*16 + t)*DDP;
    #pragma unroll
    for (int i=0;i<12;++i){
      int d = lg + 16*i;
      if (d < DDP){
        float tv = 0.0f;
        if (i < 11 && d < DD){ tv = fmaxf(v[i]-tau, 0.0f); }
        wout[d] = __float2half(tv*tv);
      }
    }
  } else if (blk == 528){
    int wv = tid>>6, l = tid&63;
    if (wv < 3){
      float v0 = m1_w[wv*64 + l];
      float mx = v0;
      #pragma unroll
      for (int m=1;m<=32;m<<=1) mx = fmaxf(mx, __shfl_xor(mx,m));
      v0 = (v0-mx)*0.5f;
      float lo=-1.0f, hi=0.0f;
      for (int it=0;it<30;++it){
        float mid = 0.5f*(lo+hi);
        float tv = fmaxf(v0-mid, 0.0f);
        float g = tv*tv;
        #pragma unroll
        for (int m=1;m<=32;m<<=1) g += __shfl_xor(g,m);
        if (g > 1.0f) lo = mid; else hi = mid;
      }
      float tau = 0.5f*(lo+hi);
      float tv = fmaxf(v0-tau, 0.0f);
      mask1[wv*64 + l] = tv*tv;
    } else if (l < 32){
      int li = l;
      float s=0.0f;
      for (int t=0;t<TT;++t){ float vv=leaves[li*TT+t]; s+=vv*vv; }
      float dn = fmaxf(sqrtf(s), 1e-12f);
      for (int t=0;t<TT;++t) lh_t[t*32+li] = leaves[li*TT+t]/dn;  // transposed [t][l]
    }
  } else { // blk == 529: m2 masks, n=80
    int wv = tid>>6, l = tid&63;
    if (wv < 3){
      float v0 = m2_w[wv*80 + l];
      float v1 = (l < 16) ? m2_w[wv*80 + 64 + l] : -1e30f;
      float mx = fmaxf(v0, v1);
      #pragma unroll
      for (int m=1;m<=32;m<<=1) mx = fmaxf(mx, __shfl_xor(mx,m));
      v0 = (v0-mx)*0.5f; v1 = (v1-mx)*0.5f;
      float lo=-1.0f, hi=0.0f;
      for (int it=0;it<30;++it){
        float mid = 0.5f*(lo+hi);
        float t0 = fmaxf(v0-mid, 0.0f), t1 = fmaxf(v1-mid, 0.0f);
        float g = t0*t0 + t1*t1;
        #pragma unroll
        for (int m=1;m<=32;m<<=1) g += __shfl_xor(g,m);
        if (g > 1.0f) lo = mid; else hi = mid;
      }
      float tau = 0.5f*(lo+hi);
      float t0 = fmaxf(v0-tau, 0.0f);
      mask2[wv*80 + l] = t0*t0;
      if (l < 16){ float t1 = fmaxf(v1-tau, 0.0f); mask2[wv*80 + 64 + l] = t1*t1; }
    }
  }
}

// ======================= k_caps: encoder -> caps_t[m][bl][DDP] (f16, zero-padded) ====
__global__ __launch_bounds__(256) void k_caps(const float* __restrict__ x,
    const float* __restrict__ init_w, const float* __restrict__ init_b,
    const float* __restrict__ ln_g, const float* __restrict__ ln_b,
    const float* __restrict__ prim_fc, __half* __restrict__ caps_t, int b0, int nrows){
  int bl = blockIdx.x, b = b0 + bl, tid = threadIdx.x;
  __shared__ float f[DD], gs[DD], bs[DD], pfs[DD*32];
  if (tid < INDIM) f[tid] = x[(size_t)b*INDIM + tid];
  if (tid < DD){ gs[tid] = ln_g[tid]; bs[tid] = ln_b[tid]; }
  for (int i = tid; i < DD*32; i += 256) pfs[i] = prim_fc[i];
  __syncthreads();
  if (tid < INITD){
    float s = init_b[tid];
    for (int k=0;k<INDIM;++k) s += f[k]*init_w[tid*INDIM+k];
    f[INDIM+tid] = s;
  }
  __syncthreads();
  int w = tid>>6, lane = tid&63;
  for (int mi = w; mi < MM; mi += 4){
    float c[3]; float sum=0.0f, sq=0.0f;
    #pragma unroll
    for (int j=0;j<3;++j){
      int d = lane + 64*j;
      float v = 0.0f;
      if (d < DD) v = (mi < 32) ? f[d]*pfs[d*32+mi] : f[d];
      c[j] = v; sum += v; sq += v*v;
    }
    #pragma unroll
    for (int off=32; off; off>>=1){ sum += __shfl_xor(sum,off); sq += __shfl_xor(sq,off); }
    float mean = sum*(1.0f/DD);
    float var  = fmaxf(sq*(1.0f/DD) - mean*mean, 0.0f);
    float rstd = rsqrtf(var + 1e-5f);
    #pragma unroll
    for (int j=0;j<3;++j){
      int d = lane + 64*j;   // covers 0..191 exactly
      float o = (d < DD) ? ((c[j]-mean)*rstd*gs[d] + bs[d]) : 0.0f;
      caps_t[((size_t)mi*nrows + bl)*DDP + d] = __float2half(o);
    }
  }
}

// ======================= k_gemm_mfma: priors[bl][m][256] via 16x16x32 f16 MFMA =======
__global__ __launch_bounds__(256) void k_gemm_mfma(const f16* __restrict__ caps_t,
    const f16* __restrict__ w2t, __half* __restrict__ priors, int nrows){
  int m = blockIdx.y, b0 = blockIdx.x*64;
  int tid = threadIdx.x;
  int wave = tid>>6, lane = tid&63;
  __shared__ f16 Al[64][40];
  __shared__ f16 Wl[256][40];
  f32x4 acc[4][4];
  #pragma unroll
  for (int i=0;i<4;++i)
    #pragma unroll
    for (int j=0;j<4;++j) acc[i][j] = (f32x4){0.f,0.f,0.f,0.f};

  int ar = tid>>2, ac0 = (tid&3)*8;
  int rg = lane&15, kg = lane>>4;

  for (int kc = 0; kc < 6; ++kc){
    *(uint4*)&Al[ar][ac0] =
        *(const uint4*)&caps_t[((size_t)m*nrows + b0 + ar)*DDP + kc*32 + ac0];
    #pragma unroll
    for (int c=0;c<4;++c)
      *(uint4*)&Wl[tid][c*8] =
          *(const uint4*)&w2t[((size_t)m*256 + tid)*DDP + kc*32 + c*8];
    __syncthreads();
    f16x8 a[4], bf[4];
    #pragma unroll
    for (int i=0;i<4;++i) a[i]  = *(const f16x8*)&Al[i*16 + rg][kg*8];
    #pragma unroll
    for (int j=0;j<4;++j) bf[j] = *(const f16x8*)&Wl[wave*64 + j*16 + rg][kg*8];
    #pragma unroll
    for (int i=0;i<4;++i)
      #pragma unroll
      for (int j=0;j<4;++j)
        acc[i][j] = __builtin_amdgcn_mfma_f32_16x16x32_f16(a[i], bf[j], acc[i][j], 0, 0, 0);
    __syncthreads();
  }
  int rg4 = kg*4, cc = rg;
  #pragma unroll
  for (int i=0;i<4;++i)
    #pragma unroll
    for (int j=0;j<4;++j)
      #pragma unroll
      for (int r=0;r<4;++r)
        priors[(size_t)(b0 + i*16 + rg4 + r)*(MM*256) + m*256 + wave*64 + j*16 + cc]
            = __float2half(acc[i][j][r]);
}

// ======================= k_route: register-resident routing ==========================
// Thread (nl, l): votes via b128 LDS loads (uint4) + fdot2 on bit-cast f16x2 dwords.
// dis via shfl butterfly; softmax without max-subtraction (wgt in [0,1)).
// PV split across lane halves.
__global__ __launch_bounds__(256) void k_route(const __half* __restrict__ priors,
    const float* __restrict__ lh_t, const float* __restrict__ thr_in,
    const float* __restrict__ cg, const float* __restrict__ cbv,
    const float* __restrict__ y, float* __restrict__ out_pred, float* __restrict__ hsel,
    int b0){
  int bl = blockIdx.x, b = b0 + bl, tid = threadIdx.x;
  __shared__ __align__(16) __half pr[MM*256];
  __shared__ float lhs[512];            // [t][l]
  __shared__ float th2s[MM*16];         // thread^2 [m][n]
  __shared__ float hid[16*16];
  __shared__ float nrm[16];
  __shared__ float yw[4];
  {
    const uint4* pbw = (const uint4*)(priors + (size_t)bl*(MM*256));
    uint4* prw = (uint4*)pr;
    for (int i = tid; i < (MM*256)/8; i += 256) prw[i] = pbw[i];   // 1056 x 16B
  }
  for (int i = tid; i < 512; i += 256) lhs[i] = lh_t[i];
  for (int i = tid; i < MM*16; i += 256){ float t = thr_in[i]; th2s[i] = t*t; }
  if (tid < 4) yw[tid] = y[(size_t)b*4 + tid];
  __syncthreads();

  int nl = tid >> 5, l = tid & 31;
  f16x2 lh2[8];
  #pragma unroll
  for (int i=0;i<8;++i){
    lh2[i][0] = (f16)lhs[(2*i)*32+l];
    lh2[i][1] = (f16)lhs[(2*i+1)*32+l];
  }

  for (int nc = 0; nc < 2; ++nc){
    int n = nc*8 + nl;
    float v[MM];
    float vsum = 0.0f;
    #pragma unroll
    for (int m=0;m<MM;++m){
      const uint4* p4 = (const uint4*)&pr[m*256 + n*16];
      uint4 u0 = p4[0], u1 = p4[1];     // 2x ds_read_b128
      float s0 = 0.0f, s1 = 0.0f;
#if __has_builtin(__builtin_amdgcn_fdot2)
      s0 = __builtin_amdgcn_fdot2(u2h2(u0.x), lh2[0], s0, false);
      s0 = __builtin_amdgcn_fdot2(u2h2(u0.y), lh2[1], s0, false);
      s0 = __builtin_amdgcn_fdot2(u2h2(u0.z), lh2[2], s0, false);
      s0 = __builtin_amdgcn_fdot2(u2h2(u0.w), lh2[3], s0, false);
      s1 = __builtin_amdgcn_fdot2(u2h2(u1.x), lh2[4], s1, false);
      s1 = __builtin_amdgcn_fdot2(u2h2(u1.y), lh2[5], s1, false);
      s1 = __builtin_amdgcn_fdot2(u2h2(u1.z), lh2[6], s1, false);
      s1 = __builtin_amdgcn_fdot2(u2h2(u1.w), lh2[7], s1, false);
#else
      {
        unsigned us[8] = {u0.x,u0.y,u0.z,u0.w,u1.x,u1.y,u1.z,u1.w};
        #pragma unroll
        for (int i=0;i<8;++i){
          f16x2 a = u2h2(us[i]);
          float p = (float)a[0]*(float)lh2[i][0] + (float)a[1]*(float)lh2[i][1];
          if (i<4) s0 += p; else s1 += p;
        }
      }
#endif
      float s = s0 + s1;
      float vv = 1.0f/(1.0f+__expf(-s));
      v[m] = vv; vsum += vv;
    }
    float mean_m = vsum*(1.0f/MM);
    // dis -> wgt (reuse v[])
    #pragma unroll
    for (int m=0;m<MM;++m){
      float dd = v[m] - mean_m;
      float sq = dd*dd;
      #pragma unroll
      for (int msk=1; msk<=16; msk<<=1) sq += __shfl_xor(sq, msk);
      v[m] = fmaxf(th2s[m*16+n] - sq*(1.0f/32), 0.0f);   // wgt in [0,1)
    }
    // softmax over m in registers, no max-subtraction needed
    float ssum = 0.0f;
    #pragma unroll
    for (int m=0;m<MM;++m){ float e = __expf(v[m]); v[m] = e; ssum += e; }
    float inv = 1.0f/ssum;
    // PV: hidden[n][t] = inv * sum_m v[m]*pr[m][n*16+t]; split m over lane halves
    int t = l & 15;
    float h = 0.0f;
    if (l < 16){
      #pragma unroll
      for (int m=0;m<=16;++m) h += v[m]*(float)((const f16*)pr)[m*256 + n*16 + t];
    } else {
      #pragma unroll
      for (int m=17;m<MM;++m) h += v[m]*(float)((const f16*)pr)[m*256 + n*16 + t];
    }
    h += __shfl_xor(h, 16);
    if (l < 16) hid[n*16+t] = h*inv;
  }
  __syncthreads();
  if (tid < 16){
    float s=0.0f, q=0.0f;
    for (int t=0;t<TT;++t){ float v2=hid[tid*16+t]; s+=v2; q+=v2*v2; }
    float mean = s*(1.0f/TT);
    float var  = fmaxf(q*(1.0f/TT)-mean*mean, 0.0f);
    float rstd = rsqrtf(var + 1e-5f);
    float nn = 0.0f;
    for (int t=0;t<TT;++t){
      float v2 = (hid[tid*16+t]-mean)*rstd*cg[t] + cbv[t];
      hid[tid*16+t] = v2; nn += v2*v2;
    }
    nrm[tid] = sqrtf(nn);
  }
  __syncthreads();
  if (tid < 4)
    out_pred[(size_t)b*4 + tid] = nrm[tid*4+0]+nrm[tid*4+1]+nrm[tid*4+2]+nrm[tid*4+3];
  if (tid < 64){
    int s2 = tid >> 4, t = tid & 15;
    float v2 = 0.0f;
    #pragma unroll
    for (int c=0;c<4;++c) v2 += yw[c]*hid[(s2*4+c)*16 + t];
    hsel[(size_t)b*64 + tid] = v2;
  }
}

// ======================= decoder (wide-grid) =========================================
__global__ __launch_bounds__(256) void k_h1(const float* __restrict__ hsel,
    const float* __restrict__ mask1, const float* __restrict__ fc1_w,
    const float* __restrict__ fc1_b, float* __restrict__ h1){
  int idx = blockIdx.x*256 + threadIdx.x;
  if (idx >= BATCH*96) return;
  int b = idx/96, j = idx%96, p = j>>5;
  float s = fc1_b[j];
  const float* hs = hsel + (size_t)b*64;
  const float* mk = mask1 + p*64;
  const float* wr = fc1_w + (size_t)j*64;
  for (int d=0; d<64; ++d) s += mk[d]*hs[d]*wr[d];
  h1[idx] = s;
}

__global__ __launch_bounds__(256) void k_stats(const float* __restrict__ h,
    float* __restrict__ stats, int F){
  int vb = blockIdx.x / F, j = blockIdx.x % F;
  float v = h[(size_t)(vb*256 + threadIdx.x)*F + j];
  float s = v, q = v*v;
  #pragma unroll
  for (int off=32; off; off>>=1){ s += __shfl_xor(s,off); q += __shfl_xor(q,off); }
  __shared__ float ps[4], pq[4];
  int w = threadIdx.x >> 6;
  if ((threadIdx.x & 63) == 0){ ps[w]=s; pq[w]=q; }
  __syncthreads();
  if (threadIdx.x == 0){
    float ss = ps[0]+ps[1]+ps[2]+ps[3];
    float qq = pq[0]+pq[1]+pq[2]+pq[3];
    float mean = ss*(1.0f/256);
    float var  = fmaxf(qq*(1.0f/256) - mean*mean, 0.0f);
    stats[(size_t)blockIdx.x*2]   = mean;
    stats[(size_t)blockIdx.x*2+1] = rsqrtf(var + 1e-5f);
  }
}

__global__ __launch_bounds__(192) void k_out1h2(const float* __restrict__ hsel,
    const float* __restrict__ h1, const float* __restrict__ stats1,
    const float* __restrict__ bn1g, const float* __restrict__ bn1b,
    const float* __restrict__ mask2, const float* __restrict__ fc2_w,
    const float* __restrict__ fc2_b, float* __restrict__ h2raw){
  int b = blockIdx.x, tid = threadIdx.x, vb = b >> 8;
  __shared__ float h2s[80];
  if (tid < 64) h2s[tid] = hsel[(size_t)b*64 + tid];
  if (tid < 16){
    float s = 0.0f;
    for (int p=0;p<3;++p){
      int ja = p*32 + tid, jb = ja + 16;
      float ha = (h1[(size_t)b*96+ja]-stats1[(vb*96+ja)*2])*stats1[(vb*96+ja)*2+1]*bn1g[ja] + bn1b[ja];
      float hb = (h1[(size_t)b*96+jb]-stats1[(vb*96+jb)*2])*stats1[(vb*96+jb)*2+1]*bn1g[jb] + bn1b[jb];
      float sg = 1.0f/(1.0f+__expf(-ha));
      s += fmaxf(sg*hb, 0.0f);
    }
    h2s[64+tid] = s;
  }
  __syncthreads();
  int p = tid >> 6;
  float s = fc2_b[tid];
  const float* mk = mask2 + p*80;
  const float* wr = fc2_w + (size_t)tid*80;
  for (int d=0; d<80; ++d) s += mk[d]*h2s[d]*wr[d];
  h2raw[(size_t)b*192 + tid] = s;
}

__global__ __launch_bounds__(128) void k_final(const float* __restrict__ h2raw,
    const float* __restrict__ stats2, const float* __restrict__ bn2g,
    const float* __restrict__ bn2b, const float* __restrict__ dec_w,
    const float* __restrict__ dec_b, float* __restrict__ out_rec){
  int b = blockIdx.x, tid = threadIdx.x, vb = b >> 8;
  __shared__ float o2[32];
  if (tid < 32){
    float s = 0.0f;
    for (int p=0;p<3;++p){
      int ja = p*64 + tid, jb = ja + 32;
      float ha = (h2raw[(size_t)b*192+ja]-stats2[(vb*192+ja)*2])*stats2[(vb*192+ja)*2+1]*bn2g[ja] + bn2b[ja];
      float hb = (h2raw[(size_t)b*192+jb]-stats2[(vb*192+jb)*2])*stats2[(vb*192+jb)*2+1]*bn2g[jb] + bn2b[jb];
      float sg = 1.0f/(1.0f+__expf(-ha));
      s += fmaxf(sg*hb, 0.0f);
    }
    o2[tid] = s;
  }
  __syncthreads();
  if (tid < INDIM){
    float r = dec_b[tid];
    #pragma unroll
    for (int o=0;o<32;++o) r += o2[o]*dec_w[tid*32+o];
    out_rec[(size_t)b*INDIM + tid] = r;
  }
}

// ======================= launch =======================
extern "C" void kernel_launch(void* const* d_in, const int* in_sizes, int n_in,
                              void* d_out, int out_size, void* d_ws, size_t ws_size,
                              hipStream_t stream){
  const float* x      = (const float*)d_in[0];
  const float* y      = (const float*)d_in[1];
  const float* init_w = (const float*)d_in[2];
  const float* init_b = (const float*)d_in[3];
  const float* eg     = (const float*)d_in[4];
  const float* ebv    = (const float*)d_in[5];
  const float* pf     = (const float*)d_in[6];
  const float* rw     = (const float*)d_in[7];
  const float* thr    = (const float*)d_in[8];
  const float* lv     = (const float*)d_in[9];
  const float* cg     = (const float*)d_in[10];
  const float* cbv    = (const float*)d_in[11];
  const float* m1w    = (const float*)d_in[12];
  const float* f1w    = (const float*)d_in[13];
  const float* f1b    = (const float*)d_in[14];
  const float* g1     = (const float*)d_in[15];
  const float* b1     = (const float*)d_in[16];
  const float* m2w    = (const float*)d_in[17];
  const float* f2w    = (const float*)d_in[18];
  const float* f2b    = (const float*)d_in[19];
  const float* g2     = (const float*)d_in[20];
  const float* b2v    = (const float*)d_in[21];
  const float* dw     = (const float*)d_in[22];
  const float* db     = (const float*)d_in[23];
  char* ws = (char*)d_ws;
  float* out = (float*)d_out;
  (void)in_sizes; (void)n_in; (void)out_size;

  // layout: [w2, caps, priors, m1, m2, lh, hsel, h1, s1, h2, s2]
  size_t offs[11];
  auto layout = [&](size_t nrows)->size_t{
    size_t o = 0; int i = 0;
    auto put = [&](size_t bytes){ offs[i++] = o; o = (o + bytes + 255) & ~(size_t)255; };
    put((size_t)MM*256*DDP*sizeof(__half));
    put((size_t)MM*nrows*DDP*sizeof(__half));
    put((size_t)nrows*MM*256*sizeof(__half));
    put(192*sizeof(float));
    put(240*sizeof(float));
    put(512*sizeof(float));
    put((size_t)BATCH*64*sizeof(float));
    put((size_t)BATCH*96*sizeof(float));
    put(16*96*2*sizeof(float));
    put((size_t)BATCH*192*sizeof(float));
    put(16*192*2*sizeof(float));
    return o;
  };
  int nrows = BATCH, nchunk = 1;
  if (layout(BATCH) > ws_size){ nrows = 1024; nchunk = 4; layout(1024); }
  __half* w2   = (__half*)(ws + offs[0]);
  __half* caps = (__half*)(ws + offs[1]);
  __half* pri  = (__half*)(ws + offs[2]);
  float*  m1   = (float*)(ws + offs[3]);
  float*  m2   = (float*)(ws + offs[4]);
  float*  lh   = (float*)(ws + offs[5]);
  float*  hsel = (float*)(ws + offs[6]);
  float*  h1   = (float*)(ws + offs[7]);
  float*  s1   = (float*)(ws + offs[8]);
  float*  h2   = (float*)(ws + offs[9]);
  float*  s2   = (float*)(ws + offs[10]);

  k_pre<<<dim3(530), dim3(256), 0, stream>>>(rw, m1w, m2w, lv, w2, m1, m2, lh);

  for (int c = 0; c < nchunk; ++c){
    int b0 = c*nrows;
    k_caps<<<dim3(nrows), dim3(256), 0, stream>>>(x, init_w, init_b, eg, ebv, pf,
        caps, b0, nrows);
    k_gemm_mfma<<<dim3(nrows/64, MM), dim3(256), 0, stream>>>(
        (const f16*)caps, (const f16*)w2, pri, nrows);
    k_route<<<dim3(nrows), dim3(256), 0, stream>>>(pri, lh, thr, cg, cbv, y,
        out, hsel, b0);
  }

  k_h1<<<dim3((BATCH*96)/256), dim3(256), 0, stream>>>(hsel, m1, f1w, f1b, h1);
  k_stats<<<dim3(16*96), dim3(256), 0, stream>>>(h1, s1, 96);
  k_out1h2<<<dim3(BATCH), dim3(192), 0, stream>>>(hsel, h1, s1, g1, b1,
      m2, f2w, f2b, h2);
  k_stats<<<dim3(16*192), dim3(256), 0, stream>>>(h2, s2, 192);
  k_final<<<dim3(BATCH), dim3(128), 0, stream>>>(h2, s2, g2, b2v, dw, db,
      out + (size_t)BATCH*NCLS);
}

// Round 14
// 407.122 us; speedup vs baseline: 1.0251x; 1.0251x over previous
//
#include <hip/hip_runtime.h>
#include <hip/hip_fp16.h>

#define BATCH 4096
#define NCLS  4
#define INDIM 100
#define INITD 64
#define DD    164     // IN_DIM + INIT_DIM
#define DDP   192     // K padded to 6*32 for MFMA
#define MM    33      // PCAP + 1
#define TT    16
#define NOUT  16      // OUT_CAPS

typedef _Float16 f16;
typedef f16 f16x8 __attribute__((ext_vector_type(8)));
typedef float f32x4 __attribute__((ext_vector_type(4)));

// ======================= k_pre: entmax + leaf norm + weight transposes ===============
// blocks 0..527: route_w entmax (one per 16-lane group).
// 528: m1 masks + leaves. 529: m2 masks. 530: iwT,w1T transposes. 531: w2T,dwT.
__global__ __launch_bounds__(256) void k_pre(const float* __restrict__ route_w,
    const float* __restrict__ m1_w, const float* __restrict__ m2_w,
    const float* __restrict__ leaves, const float* __restrict__ init_w,
    const float* __restrict__ fc1_w, const float* __restrict__ fc2_w,
    const float* __restrict__ dec_w,
    __half* __restrict__ w2t, float* __restrict__ mask1, float* __restrict__ mask2,
    float* __restrict__ lh_t, float* __restrict__ iwT, float* __restrict__ w1T,
    float* __restrict__ w2T, float* __restrict__ dwT){
  int blk = blockIdx.x, tid = threadIdx.x;
  if (blk < 528){
    const float* base = route_w + (size_t)blk*DD*16;   // [164][16] slab for (m,n)
    int l  = tid & 63;
    int t  = (tid>>6)*4 + (l&3);
    int lg = l>>2;                                     // d = lg + 16*i
    float v[11];
    float mx = -1e30f;
    #pragma unroll
    for (int i=0;i<11;++i){
      int d = lg + 16*i;
      v[i] = (d < DD) ? base[d*16 + t] : -1e30f;
      mx = fmaxf(mx, v[i]);
    }
    #pragma unroll
    for (int msk=4; msk<=32; msk<<=1) mx = fmaxf(mx, __shfl_xor(mx, msk));
    #pragma unroll
    for (int i=0;i<11;++i) v[i] = (v[i]-mx)*0.5f;
    float lo=-1.0f, hi=0.0f;
    for (int it=0; it<30; ++it){
      float mid = 0.5f*(lo+hi), g=0.0f;
      #pragma unroll
      for (int i=0;i<11;++i){ float tv = fmaxf(v[i]-mid, 0.0f); g += tv*tv; }
      #pragma unroll
      for (int msk=4; msk<=32; msk<<=1) g += __shfl_xor(g, msk);
      if (g > 1.0f) lo = mid; else hi = mid;           // uniform branch
    }
    float tau = 0.5f*(lo+hi);
    __half* wout = w2t + (size_t)(blk*16 + t)*DDP;
    #pragma unroll
    for (int i=0;i<12;++i){
      int d = lg + 16*i;
      if (d < DDP){
        float tv = 0.0f;
        if (i < 11 && d < DD){ tv = fmaxf(v[i]-tau, 0.0f); }
        wout[d] = __float2half(tv*tv);
      }
    }
  } else if (blk == 528){
    int wv = tid>>6, l = tid&63;
    if (wv < 3){
      float v0 = m1_w[wv*64 + l];
      float mx = v0;
      #pragma unroll
      for (int m=1;m<=32;m<<=1) mx = fmaxf(mx, __shfl_xor(mx,m));
      v0 = (v0-mx)*0.5f;
      float lo=-1.0f, hi=0.0f;
      for (int it=0;it<30;++it){
        float mid = 0.5f*(lo+hi);
        float tv = fmaxf(v0-mid, 0.0f);
        float g = tv*tv;
        #pragma unroll
        for (int m=1;m<=32;m<<=1) g += __shfl_xor(g,m);
        if (g > 1.0f) lo = mid; else hi = mid;
      }
      float tau = 0.5f*(lo+hi);
      float tv = fmaxf(v0-tau, 0.0f);
      mask1[wv*64 + l] = tv*tv;
    } else if (l < 32){
      int li = l;
      float s=0.0f;
      for (int t=0;t<TT;++t){ float vv=leaves[li*TT+t]; s+=vv*vv; }
      float dn = fmaxf(sqrtf(s), 1e-12f);
      for (int t=0;t<TT;++t) lh_t[t*32+li] = leaves[li*TT+t]/dn;  // transposed [t][l]
    }
  } else if (blk == 529){ // m2 masks, n=80
    int wv = tid>>6, l = tid&63;
    if (wv < 3){
      float v0 = m2_w[wv*80 + l];
      float v1 = (l < 16) ? m2_w[wv*80 + 64 + l] : -1e30f;
      float mx = fmaxf(v0, v1);
      #pragma unroll
      for (int m=1;m<=32;m<<=1) mx = fmaxf(mx, __shfl_xor(mx,m));
      v0 = (v0-mx)*0.5f; v1 = (v1-mx)*0.5f;
      float lo=-1.0f, hi=0.0f;
      for (int it=0;it<30;++it){
        float mid = 0.5f*(lo+hi);
        float t0 = fmaxf(v0-mid, 0.0f), t1 = fmaxf(v1-mid, 0.0f);
        float g = t0*t0 + t1*t1;
        #pragma unroll
        for (int m=1;m<=32;m<<=1) g += __shfl_xor(g,m);
        if (g > 1.0f) lo = mid; else hi = mid;
      }
      float tau = 0.5f*(lo+hi);
      float t0 = fmaxf(v0-tau, 0.0f);
      mask2[wv*80 + l] = t0*t0;
      if (l < 16){ float t1 = fmaxf(v1-tau, 0.0f); mask2[wv*80 + 64 + l] = t1*t1; }
    }
  } else if (blk == 530){
    // iwT[k][o] = init_w[o][k]; w1T[d][j] = fc1_w[j][d]
    for (int i=tid; i<INDIM*INITD; i+=256){ int k=i>>6, o=i&63; iwT[i] = init_w[o*INDIM+k]; }
    for (int i=tid; i<64*96;     i+=256){ int d=i/96, j=i-96*d; w1T[i] = fc1_w[j*64+d]; }
  } else { // blk == 531
    // w2T[d][j] = fc2_w[j][d]; dwT[o][k] = dec_w[k][o]
    for (int i=tid; i<80*192;  i+=256){ int d=i/192, j=i-192*d; w2T[i] = fc2_w[j*80+d]; }
    for (int i=tid; i<32*INDIM;i+=256){ int o=i/INDIM, k=i-INDIM*o; dwT[i] = dec_w[k*32+o]; }
  }
}

// ======================= k_caps: encoder -> caps_t[m][bl][DDP] (f16, zero-padded) ====
__global__ __launch_bounds__(256) void k_caps(const float* __restrict__ x,
    const float* __restrict__ iwT, const float* __restrict__ init_b,
    const float* __restrict__ ln_g, const float* __restrict__ ln_b,
    const float* __restrict__ prim_fc, __half* __restrict__ caps_t, int b0, int nrows){
  int bl = blockIdx.x, b = b0 + bl, tid = threadIdx.x;
  __shared__ float f[DD], gs[DD], bs[DD], pfs[DD*32];
  if (tid < INDIM) f[tid] = x[(size_t)b*INDIM + tid];
  if (tid < DD){ gs[tid] = ln_g[tid]; bs[tid] = ln_b[tid]; }
  for (int i = tid; i < (DD*32)/4; i += 256) ((float4*)pfs)[i] = ((const float4*)prim_fc)[i];
  __syncthreads();
  {
    // init FC: o = tid>>2 (0..63), kg = tid&3 covers 25 k's; quad shfl reduce.
    int o = tid>>2, kg = tid&3, k0 = kg*25;
    float s = 0.0f;
    #pragma unroll 5
    for (int k=0;k<25;++k) s += f[k0+k]*iwT[(k0+k)*64 + o];
    s += __shfl_xor(s,1);
    s += __shfl_xor(s,2);
    if (kg == 0) f[INDIM+o] = s + init_b[o];
  }
  __syncthreads();
  int w = tid>>6, lane = tid&63;
  for (int mi = w; mi < MM; mi += 4){
    float c[3]; float sum=0.0f, sq=0.0f;
    #pragma unroll
    for (int j=0;j<3;++j){
      int d = lane + 64*j;
      float v = 0.0f;
      if (d < DD) v = (mi < 32) ? f[d]*pfs[d*32+mi] : f[d];
      c[j] = v; sum += v; sq += v*v;
    }
    #pragma unroll
    for (int off=32; off; off>>=1){ sum += __shfl_xor(sum,off); sq += __shfl_xor(sq,off); }
    float mean = sum*(1.0f/DD);
    float var  = fmaxf(sq*(1.0f/DD) - mean*mean, 0.0f);
    float rstd = rsqrtf(var + 1e-5f);
    #pragma unroll
    for (int j=0;j<3;++j){
      int d = lane + 64*j;   // covers 0..191 exactly
      float o = (d < DD) ? ((c[j]-mean)*rstd*gs[d] + bs[d]) : 0.0f;
      caps_t[((size_t)mi*nrows + bl)*DDP + d] = __float2half(o);
    }
  }
}

// ======================= k_gemm_mfma: priors[bl][m][256] via 16x16x32 f16 MFMA =======
__global__ __launch_bounds__(256) void k_gemm_mfma(const f16* __restrict__ caps_t,
    const f16* __restrict__ w2t, __half* __restrict__ priors, int nrows){
  int m = blockIdx.y, b0 = blockIdx.x*64;
  int tid = threadIdx.x;
  int wave = tid>>6, lane = tid&63;
  __shared__ f16 Al[64][40];
  __shared__ f16 Wl[256][40];
  f32x4 acc[4][4];
  #pragma unroll
  for (int i=0;i<4;++i)
    #pragma unroll
    for (int j=0;j<4;++j) acc[i][j] = (f32x4){0.f,0.f,0.f,0.f};

  int ar = tid>>2, ac0 = (tid&3)*8;
  int rg = lane&15, kg = lane>>4;

  for (int kc = 0; kc < 6; ++kc){
    *(uint4*)&Al[ar][ac0] =
        *(const uint4*)&caps_t[((size_t)m*nrows + b0 + ar)*DDP + kc*32 + ac0];
    #pragma unroll
    for (int c=0;c<4;++c)
      *(uint4*)&Wl[tid][c*8] =
          *(const uint4*)&w2t[((size_t)m*256 + tid)*DDP + kc*32 + c*8];
    __syncthreads();
    f16x8 a[4], bf[4];
    #pragma unroll
    for (int i=0;i<4;++i) a[i]  = *(const f16x8*)&Al[i*16 + rg][kg*8];
    #pragma unroll
    for (int j=0;j<4;++j) bf[j] = *(const f16x8*)&Wl[wave*64 + j*16 + rg][kg*8];
    #pragma unroll
    for (int i=0;i<4;++i)
      #pragma unroll
      for (int j=0;j<4;++j)
        acc[i][j] = __builtin_amdgcn_mfma_f32_16x16x32_f16(a[i], bf[j], acc[i][j], 0, 0, 0);
    __syncthreads();
  }
  int rg4 = kg*4, cc = rg;
  #pragma unroll
  for (int i=0;i<4;++i)
    #pragma unroll
    for (int j=0;j<4;++j)
      #pragma unroll
      for (int r=0;r<4;++r)
        priors[(size_t)(b0 + i*16 + rg4 + r)*(MM*256) + m*256 + wave*64 + j*16 + cc]
            = __float2half(acc[i][j][r]);
}

// ======================= k_route: register-resident routing (round-10 core) ==========
// Thread (nl, l): votes v[m] in registers (f16x8 LDS loads, scalar cvt+FMA),
// dis via shfl butterfly, softmax in registers WITHOUT max-subtraction
// (wgt in [0,1)), PV split across lane halves.
__global__ __launch_bounds__(256) void k_route(const __half* __restrict__ priors,
    const float* __restrict__ lh_t, const float* __restrict__ thr_in,
    const float* __restrict__ cg, const float* __restrict__ cbv,
    const float* __restrict__ y, float* __restrict__ out_pred, float* __restrict__ hsel,
    int b0){
  int bl = blockIdx.x, b = b0 + bl, tid = threadIdx.x;
  __shared__ __align__(16) __half pr[MM*256];
  __shared__ float lhs[512];            // [t][l]
  __shared__ float th2s[MM*16];         // thread^2 [m][n]
  __shared__ float hid[16*16];
  __shared__ float nrm[16];
  __shared__ float yw[4];
  {
    const uint4* pbw = (const uint4*)(priors + (size_t)bl*(MM*256));
    uint4* prw = (uint4*)pr;
    for (int i = tid; i < (MM*256)/8; i += 256) prw[i] = pbw[i];
  }
  for (int i = tid; i < 512; i += 256) lhs[i] = lh_t[i];
  for (int i = tid; i < MM*16; i += 256){ float t = thr_in[i]; th2s[i] = t*t; }
  if (tid < 4) yw[tid] = y[(size_t)b*4 + tid];
  __syncthreads();

  int nl = tid >> 5, l = tid & 31;
  float lh_reg[TT];
  #pragma unroll
  for (int t=0;t<TT;++t) lh_reg[t] = lhs[t*32+l];

  for (int nc = 0; nc < 2; ++nc){
    int n = nc*8 + nl;
    float v[MM];
    float vsum = 0.0f;
    #pragma unroll
    for (int m=0;m<MM;++m){
      const f16* p0 = (const f16*)&pr[m*256 + n*16];
      f16x8 a0 = *(const f16x8*)p0;
      f16x8 a1 = *(const f16x8*)(p0+8);
      float s = 0.0f;
      #pragma unroll
      for (int t=0;t<8;++t) s += lh_reg[t]*(float)a0[t];
      #pragma unroll
      for (int t=0;t<8;++t) s += lh_reg[8+t]*(float)a1[t];
      float vv = 1.0f/(1.0f+__expf(-s));
      v[m] = vv; vsum += vv;
    }
    float mean_m = vsum*(1.0f/MM);
    // dis -> wgt (reuse v[])
    #pragma unroll
    for (int m=0;m<MM;++m){
      float dd = v[m] - mean_m;
      float sq = dd*dd;
      #pragma unroll
      for (int msk=1; msk<=16; msk<<=1) sq += __shfl_xor(sq, msk);
      v[m] = fmaxf(th2s[m*16+n] - sq*(1.0f/32), 0.0f);   // wgt in [0,1)
    }
    // softmax over m in registers, no max-subtraction needed (wgt bounded)
    float ssum = 0.0f;
    #pragma unroll
    for (int m=0;m<MM;++m){ float e = __expf(v[m]); v[m] = e; ssum += e; }
    float inv = 1.0f/ssum;
    // PV: hidden[n][t] = inv * sum_m v[m]*pr[m][n*16+t]; split m over lane halves
    int t = l & 15;
    float h = 0.0f;
    if (l < 16){
      #pragma unroll
      for (int m=0;m<=16;++m) h += v[m]*(float)((const f16*)pr)[m*256 + n*16 + t];
    } else {
      #pragma unroll
      for (int m=17;m<MM;++m) h += v[m]*(float)((const f16*)pr)[m*256 + n*16 + t];
    }
    h += __shfl_xor(h, 16);
    if (l < 16) hid[n*16+t] = h*inv;
  }
  __syncthreads();
  if (tid < 16){
    float s=0.0f, q=0.0f;
    for (int t=0;t<TT;++t){ float v2=hid[tid*16+t]; s+=v2; q+=v2*v2; }
    float mean = s*(1.0f/TT);
    float var  = fmaxf(q*(1.0f/TT)-mean*mean, 0.0f);
    float rstd = rsqrtf(var + 1e-5f);
    float nn = 0.0f;
    for (int t=0;t<TT;++t){
      float v2 = (hid[tid*16+t]-mean)*rstd*cg[t] + cbv[t];
      hid[tid*16+t] = v2; nn += v2*v2;
    }
    nrm[tid] = sqrtf(nn);
  }
  __syncthreads();
  if (tid < 4)
    out_pred[(size_t)b*4 + tid] = nrm[tid*4+0]+nrm[tid*4+1]+nrm[tid*4+2]+nrm[tid*4+3];
  if (tid < 64){
    int s2 = tid >> 4, t = tid & 15;
    float v2 = 0.0f;
    #pragma unroll
    for (int c=0;c<4;++c) v2 += yw[c]*hid[(s2*4+c)*16 + t];
    hsel[(size_t)b*64 + tid] = v2;
  }
}

// ======================= decoder (wide-grid, transposed weights) =====================
__global__ __launch_bounds__(256) void k_h1(const float* __restrict__ hsel,
    const float* __restrict__ mask1, const float* __restrict__ w1T,
    const float* __restrict__ fc1_b, float* __restrict__ h1){
  int idx = blockIdx.x*256 + threadIdx.x;
  if (idx >= BATCH*96) return;
  int b = idx/96, j = idx%96, p = j>>5;
  float s = fc1_b[j];
  const float* hs = hsel + (size_t)b*64;
  const float* mk = mask1 + p*64;
  for (int d=0; d<64; ++d) s += mk[d]*hs[d]*w1T[d*96+j];   // coalesced in j
  h1[idx] = s;
}

__global__ __launch_bounds__(256) void k_stats(const float* __restrict__ h,
    float* __restrict__ stats, int F){
  int vb = blockIdx.x / F, j = blockIdx.x % F;
  float v = h[(size_t)(vb*256 + threadIdx.x)*F + j];
  float s = v, q = v*v;
  #pragma unroll
  for (int off=32; off; off>>=1){ s += __shfl_xor(s,off); q += __shfl_xor(q,off); }
  __shared__ float ps[4], pq[4];
  int w = threadIdx.x >> 6;
  if ((threadIdx.x & 63) == 0){ ps[w]=s; pq[w]=q; }
  __syncthreads();
  if (threadIdx.x == 0){
    float ss = ps[0]+ps[1]+ps[2]+ps[3];
    float qq = pq[0]+pq[1]+pq[2]+pq[3];
    float mean = ss*(1.0f/256);
    float var  = fmaxf(qq*(1.0f/256) - mean*mean, 0.0f);
    stats[(size_t)blockIdx.x*2]   = mean;
    stats[(size_t)blockIdx.x*2+1] = rsqrtf(var + 1e-5f);
  }
}

__global__ __launch_bounds__(192) void k_out1h2(const float* __restrict__ hsel,
    const float* __restrict__ h1, const float* __restrict__ stats1,
    const float* __restrict__ bn1g, const float* __restrict__ bn1b,
    const float* __restrict__ mask2, const float* __restrict__ w2T,
    const float* __restrict__ fc2_b, float* __restrict__ h2raw){
  int b = blockIdx.x, tid = threadIdx.x, vb = b >> 8;
  __shared__ float h2s[80];
  if (tid < 64) h2s[tid] = hsel[(size_t)b*64 + tid];
  if (tid < 16){
    float s = 0.0f;
    for (int p=0;p<3;++p){
      int ja = p*32 + tid, jb = ja + 16;
      float ha = (h1[(size_t)b*96+ja]-stats1[(vb*96+ja)*2])*stats1[(vb*96+ja)*2+1]*bn1g[ja] + bn1b[ja];
      float hb = (h1[(size_t)b*96+jb]-stats1[(vb*96+jb)*2])*stats1[(vb*96+jb)*2+1]*bn1g[jb] + bn1b[jb];
      float sg = 1.0f/(1.0f+__expf(-ha));
      s += fmaxf(sg*hb, 0.0f);
    }
    h2s[64+tid] = s;
  }
  __syncthreads();
  int p = tid >> 6;
  float s = fc2_b[tid];
  const float* mk = mask2 + p*80;
  for (int d=0; d<80; ++d) s += mk[d]*h2s[d]*w2T[d*192+tid];  // coalesced in tid
  h2raw[(size_t)b*192 + tid] = s;
}

__global__ __launch_bounds__(128) void k_final(const float* __restrict__ h2raw,
    const float* __restrict__ stats2, const float* __restrict__ bn2g,
    const float* __restrict__ bn2b, const float* __restrict__ dwT,
    const float* __restrict__ dec_b, float* __restrict__ out_rec){
  int b = blockIdx.x, tid = threadIdx.x, vb = b >> 8;
  __shared__ float o2[32];
  if (tid < 32){
    float s = 0.0f;
    for (int p=0;p<3;++p){
      int ja = p*64 + tid, jb = ja + 32;
      float ha = (h2raw[(size_t)b*192+ja]-stats2[(vb*192+ja)*2])*stats2[(vb*192+ja)*2+1]*bn2g[ja] + bn2b[ja];
      float hb = (h2raw[(size_t)b*192+jb]-stats2[(vb*192+jb)*2])*stats2[(vb*192+jb)*2+1]*bn2g[jb] + bn2b[jb];
      float sg = 1.0f/(1.0f+__expf(-ha));
      s += fmaxf(sg*hb, 0.0f);
    }
    o2[tid] = s;
  }
  __syncthreads();
  if (tid < INDIM){
    float r = dec_b[tid];
    #pragma unroll
    for (int o=0;o<32;++o) r += o2[o]*dwT[o*INDIM+tid];   // coalesced in tid
    out_rec[(size_t)b*INDIM + tid] = r;
  }
}

// ======================= launch =======================
extern "C" void kernel_launch(void* const* d_in, const int* in_sizes, int n_in,
                              void* d_out, int out_size, void* d_ws, size_t ws_size,
                              hipStream_t stream){
  const float* x      = (const float*)d_in[0];
  const float* y      = (const float*)d_in[1];
  const float* init_w = (const float*)d_in[2];
  const float* init_b = (const float*)d_in[3];
  const float* eg     = (const float*)d_in[4];
  const float* ebv    = (const float*)d_in[5];
  const float* pf     = (const float*)d_in[6];
  const float* rw     = (const float*)d_in[7];
  const float* thr    = (const float*)d_in[8];
  const float* lv     = (const float*)d_in[9];
  const float* cg     = (const float*)d_in[10];
  const float* cbv    = (const float*)d_in[11];
  const float* m1w    = (const float*)d_in[12];
  const float* f1w    = (const float*)d_in[13];
  const float* f1b    = (const float*)d_in[14];
  const float* g1     = (const float*)d_in[15];
  const float* b1     = (const float*)d_in[16];
  const float* m2w    = (const float*)d_in[17];
  const float* f2w    = (const float*)d_in[18];
  const float* f2b    = (const float*)d_in[19];
  const float* g2     = (const float*)d_in[20];
  const float* b2v    = (const float*)d_in[21];
  const float* dw     = (const float*)d_in[22];
  const float* db     = (const float*)d_in[23];
  char* ws = (char*)d_ws;
  float* out = (float*)d_out;
  (void)in_sizes; (void)n_in; (void)out_size;

  // layout: [w2, caps, priors, m1, m2, lh, hsel, h1, s1, h2, s2, iwT, w1T, w2T, dwT]
  size_t offs[15];
  auto layout = [&](size_t nrows)->size_t{
    size_t o = 0; int i = 0;
    auto put = [&](size_t bytes){ offs[i++] = o; o = (o + bytes + 255) & ~(size_t)255; };
    put((size_t)MM*256*DDP*sizeof(__half));
    put((size_t)MM*nrows*DDP*sizeof(__half));
    put((size_t)nrows*MM*256*sizeof(__half));
    put(192*sizeof(float));
    put(240*sizeof(float));
    put(512*sizeof(float));
    put((size_t)BATCH*64*sizeof(float));
    put((size_t)BATCH*96*sizeof(float));
    put(16*96*2*sizeof(float));
    put((size_t)BATCH*192*sizeof(float));
    put(16*192*2*sizeof(float));
    put(INDIM*INITD*sizeof(float));   // iwT
    put(64*96*sizeof(float));         // w1T
    put(80*192*sizeof(float));        // w2T
    put(32*INDIM*sizeof(float));      // dwT
    return o;
  };
  int nrows = BATCH, nchunk = 1;
  if (layout(BATCH) > ws_size){ nrows = 1024; nchunk = 4; layout(1024); }
  __half* w2   = (__half*)(ws + offs[0]);
  __half* caps = (__half*)(ws + offs[1]);
  __half* pri  = (__half*)(ws + offs[2]);
  float*  m1   = (float*)(ws + offs[3]);
  float*  m2   = (float*)(ws + offs[4]);
  float*  lh   = (float*)(ws + offs[5]);
  float*  hsel = (float*)(ws + offs[6]);
  float*  h1   = (float*)(ws + offs[7]);
  float*  s1   = (float*)(ws + offs[8]);
  float*  h2   = (float*)(ws + offs[9]);
  float*  s2   = (float*)(ws + offs[10]);
  float*  iwT  = (float*)(ws + offs[11]);
  float*  w1T  = (float*)(ws + offs[12]);
  float*  w2T  = (float*)(ws + offs[13]);
  float*  dwT  = (float*)(ws + offs[14]);

  k_pre<<<dim3(532), dim3(256), 0, stream>>>(rw, m1w, m2w, lv, init_w, f1w, f2w, dw,
      w2, m1, m2, lh, iwT, w1T, w2T, dwT);

  for (int c = 0; c < nchunk; ++c){
    int b0 = c*nrows;
    k_caps<<<dim3(nrows), dim3(256), 0, stream>>>(x, iwT, init_b, eg, ebv, pf,
        caps, b0, nrows);
    k_gemm_mfma<<<dim3(nrows/64, MM), dim3(256), 0, stream>>>(
        (const f16*)caps, (const f16*)w2, pri, nrows);
    k_route<<<dim3(nrows), dim3(256), 0, stream>>>(pri, lh, thr, cg, cbv, y,
        out, hsel, b0);
  }

  k_h1<<<dim3((BATCH*96)/256), dim3(256), 0, stream>>>(hsel, m1, w1T, f1b, h1);
  k_stats<<<dim3(16*96), dim3(256), 0, stream>>>(h1, s1, 96);
  k_out1h2<<<dim3(BATCH), dim3(192), 0, stream>>>(hsel, h1, s1, g1, b1,
      m2, w2T, f2b, h2);
  k_stats<<<dim3(16*192), dim3(256), 0, stream>>>(h2, s2, 192);
  k_final<<<dim3(BATCH), dim3(128), 0, stream>>>(h2, s2, g2, b2v, dwT, db,
      out + (size_t)BATCH*NCLS);
}